// Round 13
// baseline (311.738 us; speedup 1.0000x reference)
//
#include <hip/hip_runtime.h>

#define NN 50000
#define FF 300
#define DD 128
#define HH 4
#define CC 32
#define EE 640000
#define RR 200
#define LL 2
#define SB ((NN + 255) / 256)     // scan blocks = 196
#define PK 320                    // proj K padded to multiple of 64
#define WCONV (2 * 128 * 128)     // layer-1 wl/wr transposed fp16
#define WTOT (2 * 128 * PK + WCONV)
// prep sections (chunked x4, dense per-instruction accesses)
#define HB2 (EE / 1024)           // hist blocks: 625, 4 edges/thread
#define WB2 (WCONV / 1024)        // wconv blocks: 32, 4 elems/thread
#define FB2 80                    // fold blocks: 8 k's each (4/half, shared W stream)
#define RB2 100                   // relproj blocks: 4 r's each (2/half, shared W)
#define PB (HB2 + WB2 + FB2 + 1 + RB2)   // prep grid: 838
#define NSC 256                   // scatter blocks fused into gemm0: 32 per XCD
#define NDX (NN / 8)              // dst range per XCD: 6250
#define ESTR (EE / 32)            // edge stripe per group-rank: 20000

typedef unsigned short u16;
typedef unsigned int u32;
typedef unsigned long long u64;
typedef _Float16 h2   __attribute__((ext_vector_type(2)));
typedef _Float16 half8 __attribute__((ext_vector_type(8)));  // MFMA A/B frag (4 VGPRs)
typedef __attribute__((ext_vector_type(4))) float floatx4;   // MFMA accumulator
typedef u32 u32x4 __attribute__((ext_vector_type(4)));       // 16B packed-half load
typedef u32 u32x2 __attribute__((ext_vector_type(2)));

__device__ __forceinline__ u16 f2h(float f) {
    union { _Float16 h; u16 u; } v; v.h = (_Float16)f; return v.u;
}
__device__ __forceinline__ h2 u2h2(u32 p) {
    union { u32 u; h2 h; } v; v.u = p; return v.h;
}
__device__ __forceinline__ h2 hmax2(h2 a, h2 b) {
#if __has_builtin(__builtin_elementwise_max)
    return __builtin_elementwise_max(a, b);
#else
    h2 r; r.x = a.x > b.x ? a.x : b.x; r.y = a.y > b.y ? a.y : b.y; return r;
#endif
}
__device__ __forceinline__ float hdot2(h2 a, h2 b, float c) {
#if __has_builtin(__builtin_amdgcn_fdot2)
    return __builtin_amdgcn_fdot2(a, b, c, false);
#else
    return c + (float)a.x * (float)b.x + (float)a.y * (float)b.y;
#endif
}
// async global->LDS DMA, 16 B per lane; dest = lds_base + lane*16 (wave-uniform base)
__device__ __forceinline__ void glds16(const void* g, void* l) {
    using gp = const unsigned int __attribute__((address_space(1)))*;
    using lp = unsigned int __attribute__((address_space(3)))*;
    __builtin_amdgcn_global_load_lds((gp)(u64)g, (lp)(u64)l, 16, 0, 0);
}

// block-wide (256 threads) scan: returns exclusive prefix of v; *total = block sum
__device__ __forceinline__ int block_excl_scan(int v, int* lds4, int* total) {
    int lane = threadIdx.x & 63, wid = threadIdx.x >> 6;
    int x = v;
    #pragma unroll
    for (int off = 1; off < 64; off <<= 1) {
        int y = __shfl_up(x, off, 64);
        if (lane >= off) x += y;
    }
    if (lane == 63) lds4[wid] = x;
    __syncthreads();
    int add = 0;
    #pragma unroll
    for (int w = 0; w < 4; w++) add += (w < wid) ? lds4[w] : 0;
    *total = lds4[0] + lds4[1] + lds4[2] + lds4[3];
    return x + add - v;
}

// ---------------- fused prep:
// hist+rank | layer1 wconv | layer0 fold (8k/blk, shared W) | biasfold | relproj
// hist KEEPS the atomic return value: rank[e] = edge's arrival index within its
// dst -> the later scatter needs NO atomic at all (pos = offsets+bsum+rank).
__global__ __launch_bounds__(256)
void prep_kernel(const int* __restrict__ ei, int* __restrict__ counts,
                 int* __restrict__ rank,
                 const float* __restrict__ proj_w, const float* __restrict__ w_l,
                 const float* __restrict__ w_r, u16* __restrict__ wt,
                 const float* __restrict__ rel_emb, const float* __restrict__ w_e,
                 u16* __restrict__ erel, const float* __restrict__ proj_b,
                 const float* __restrict__ b_l, const float* __restrict__ b_r,
                 float* __restrict__ fbias)
{
    __shared__ float sm[8 * DD];   // 4 KB scratch, aliased per section
    int b = blockIdx.x, tid = threadIdx.x;
    if (b < HB2) {
        // degree histogram + per-edge rank capture: 4 edges/thread
        #pragma unroll
        for (int j = 0; j < 4; j++) {
            int e = b * 1024 + j * 256 + tid;            // < EE exactly
            int r = atomicAdd(&counts[ei[EE + e]], 1);
            rank[e] = r;                                 // coalesced 4B store
        }
    } else if (b < HB2 + WB2) {
        // layer-1 weights: fp32 [k][n] -> fp16 wt[n][k], segs [wl1][wr1]; 4/thread
        #pragma unroll
        for (int j = 0; j < 4; j++) {
            int i = (b - HB2) * 1024 + j * 256 + tid;    // < 32768 exactly
            int seg = i >> 14;                           // 0 = wl1, 1 = wr1
            int r = i & 16383;
            int n = r >> 7, k = r & 127;
            const float* src = (seg == 0 ? w_l : w_r) + (size_t)DD * DD;  // layer 1
            wt[2 * 128 * PK + i] = f2h(src[(size_t)k * DD + n]);
        }
    } else if (b < HB2 + WB2 + FB2) {
        // fused layer-0 weights: F[k][n] = sum_j Wp[k][j]*W{l,r}0[j][n]
        // block: one lr, 8 k's (half handles 4, sharing one W-column stream)
        int bb = b - HB2 - WB2;
        int lr = bb / 40, kg = bb % 40;
        int half = tid >> 7, d = tid & 127;
        int k0 = kg * 8 + half * 4;
        float* rv = sm + half * 4 * DD;
        #pragma unroll
        for (int kk = 0; kk < 4; kk++)
            rv[kk * DD + d] = (k0 + kk < FF) ? proj_w[(size_t)(k0 + kk) * DD + d] : 0.f;
        __syncthreads();
        const float* W = lr ? w_r : w_l;                 // layer 0
        float acc[4] = {0.f, 0.f, 0.f, 0.f};
        #pragma unroll 8
        for (int j = 0; j < DD; j++) {
            float wv = W[(size_t)j * DD + d];
            #pragma unroll
            for (int kk = 0; kk < 4; kk++) acc[kk] += rv[kk * DD + j] * wv;
        }
        u16 o[4];
        #pragma unroll
        for (int kk = 0; kk < 4; kk++) o[kk] = f2h(acc[kk]);
        *(u32x2*)(wt + (size_t)lr * 128 * PK + (size_t)d * PK + k0) = *(u32x2*)o;
    } else if (b == HB2 + WB2 + FB2) {
        // fused layer-0 bias: fb = b_{l,r}0 + proj_b @ W{l,r}0  (fp32)
        int half = tid >> 7, d = tid & 127;
        if (tid < DD) sm[tid] = proj_b[tid];
        __syncthreads();
        const float* W = half ? w_r : w_l;
        float acc = half ? b_r[d] : b_l[d];
        #pragma unroll 8
        for (int j = 0; j < DD; j++) acc += sm[j] * W[(size_t)j * DD + d];
        fbias[half * DD + d] = acc;
    } else {
        // erel[(l*RR+r)][d] = rel_emb[r,:] @ w_e[l][:,d]
        // block: one l, 4 r's (half handles 2, sharing W stream)
        int bb = b - (HB2 + WB2 + FB2 + 1);
        int l = bb / 50, rg = bb % 50;
        int half = tid >> 7, d = tid & 127;
        int r0 = rg * 4 + half * 2;
        float* rv = sm + half * 2 * DD;
        #pragma unroll
        for (int rr = 0; rr < 2; rr++)
            rv[rr * DD + d] = rel_emb[(size_t)(r0 + rr) * DD + d];
        __syncthreads();
        const float* W = w_e + (size_t)l * DD * DD;
        float acc[2] = {0.f, 0.f};
        #pragma unroll 8
        for (int j = 0; j < DD; j++) {
            float wv = W[(size_t)j * DD + d];
            #pragma unroll
            for (int rr = 0; rr < 2; rr++) acc[rr] += rv[rr * DD + j] * wv;
        }
        #pragma unroll
        for (int rr = 0; rr < 2; rr++)
            erel[(size_t)(l * RR + r0 + rr) * DD + d] = f2h(acc[rr]);
    }
}

// ---------------- dual-output MFMA GEMM, global_load_lds staging, 64x256 tile,
// 8 waves (wave owns 32 cols; waves 0-3 -> C1, 4-7 -> C2), BK=64, 2 barriers/step.
// AF32=false: A fp16 [M][K] direct (xb), 1 A-DMA/thread/step, 8KB A-LDS.
// AF32=true : A fp32 gathered from nf via rowidx (convert folded into fragment
//   load, RTE-identical to a pre-converted table). Tail cols 256..319 guarded.
// FUSE: blocks [0,NSC) run the XCD-PARTITIONED atomic-free CSR scatter.
//   dstorder pos ranges are contiguous per dst range; block (b&7) handles dst
//   range [(b&7)*NDX, +NDX) so every dstorder cache line is written by ONE XCD's
//   L2 only (block->XCD is round-robin) -> the ~16 writes/line MERGE before
//   writeback, killing the 10x partial-line write amplification. Each of the 32
//   blocks per XCD re-reads one full edge stripe (coalesced, L2/L3-resident).
template<int K, bool AF32, bool FUSE>
__global__ __launch_bounds__(512)
void gemm_gll_kernel(const void* __restrict__ A_, const int* __restrict__ rowidx,
                     const u16* __restrict__ BT1, const float* __restrict__ bias1,
                     u16* __restrict__ C1,
                     const u16* __restrict__ BT2, const float* __restrict__ bias2,
                     u16* __restrict__ C2, int M,
                     const int* __restrict__ ei, const int* __restrict__ et,
                     const int* __restrict__ offsets, const int* __restrict__ bsum,
                     const int* __restrict__ rank, u32* __restrict__ dstorder)
{
    __shared__ float AsF[AF32 ? 4096 : 2048];   // 16 KB fp32 | 8 KB fp16
    __shared__ u16 Bs[256 * 64];                // 32 KB
    int tid  = threadIdx.x;
    if constexpr (FUSE) {
        if (blockIdx.x < NSC) {
            // XCD-partitioned scatter: dst range by blockIdx&7, stripe by >>3
            int dlo = ((int)blockIdx.x & 7) * NDX;
            int dhi = dlo + NDX;
            int base = ((int)blockIdx.x >> 3) * ESTR;
            for (int k = tid; k < ESTR; k += 512) {
                int e = base + k;
                int d = ei[EE + e];
                if (d >= dlo && d < dhi) {
                    int pos = offsets[d] + bsum[d >> 8] + rank[e];
                    dstorder[pos] = (u32)ei[e] | ((u32)et[e] << 16);
                }
            }
            return;
        }
    }
    int bid  = FUSE ? ((int)blockIdx.x - NSC) : (int)blockIdx.x;
    int m0   = bid * 64;
    int wave = tid >> 6, lane = tid & 63;
    int quad = lane >> 4, l16 = lane & 15;

    floatx4 acc[4][2];
    #pragma unroll
    for (int i = 0; i < 4; i++)
        #pragma unroll
        for (int j = 0; j < 2; j++) acc[i][j] = (floatx4){0.f, 0.f, 0.f, 0.f};

    // ---- B staging source pointers (per lane, swizzled); ldb == K
    const char* bp[4];
    #pragma unroll
    for (int c = 0; c < 4; c++) {
        int rowB = wave * 32 + c * 8 + (lane >> 3);   // 0..255
        const u16* base = (rowB < 128) ? BT1 : BT2;
        int br = rowB & 127;
        bp[c] = (const char*)(base + (size_t)br * K)
              + (((lane & 7) << 4) ^ ((br & 7) << 4));
    }
    char* AsW = (char*)AsF;
    char* BsW = (char*)Bs;
    const char* AsR = (const char*)AsF;
    const char* BsR = (const char*)Bs;

    // ---- A staging source pointers
    const char* ap1; const char* ap2; const float* s1; const float* s2;
    int r1, r2;
    if constexpr (AF32) {
        r1 = wave * 4 + (lane >> 4);                 // rows 0..31
        r2 = r1 + 32;                                // rows 32..63
        int g1 = m0 + r1; if (g1 >= M) g1 = M - 1;
        int g2 = m0 + r2; if (g2 >= M) g2 = M - 1;
        s1 = (const float*)A_ + (size_t)rowidx[g1] * FF;
        s2 = (const float*)A_ + (size_t)rowidx[g2] * FF;
        ap1 = (const char*)s1 + (((lane & 15) ^ (r1 & 7)) * 16);
        ap2 = (const char*)s2 + (((lane & 15) ^ (r2 & 7)) * 16);
    } else {
        int arl = wave * 8 + (lane >> 3);
        int arg = m0 + arl; if (arg >= M) arg = M - 1;
        ap1 = (const char*)((const u16*)A_ + (size_t)arg * K)
            + (((lane & 7) << 4) ^ ((arl & 7) << 4));
        ap2 = nullptr; s1 = s2 = nullptr; r1 = r2 = 0;
    }
    int axor16 = (l16 & 7) << 4;

    // compute phase for one 64-col LDS tile (cols kk..kk+64 resident)
    auto compute = [&]() {
        #pragma unroll
        for (int s2i = 0; s2i < 2; s2i++) {
            half8 af[4], bf[2];
            if constexpr (AF32) {
                int c0 = s2i * 8 + quad * 2;           // 16B chunk idx (4 floats)
                #pragma unroll
                for (int i = 0; i < 4; i++) {
                    int row = i * 16 + l16;
                    const char* rb = AsR + row * 256;
                    float4 lo = *(const float4*)(rb + ((c0 ^ (row & 7)) * 16));
                    float4 hi = *(const float4*)(rb + (((c0 + 1) ^ (row & 7)) * 16));
                    u16 o[8];
                    o[0] = f2h(lo.x); o[1] = f2h(lo.y); o[2] = f2h(lo.z); o[3] = f2h(lo.w);
                    o[4] = f2h(hi.x); o[5] = f2h(hi.y); o[6] = f2h(hi.z); o[7] = f2h(hi.w);
                    af[i] = *(half8*)o;
                }
            } else {
                int cb = (s2i * 64 + quad * 16) ^ axor16;
                #pragma unroll
                for (int i = 0; i < 4; i++)
                    af[i] = *(const half8*)(AsR + (i * 16 + l16) * 128 + cb);
            }
            int cbB = (s2i * 64 + quad * 16) ^ axor16;
            #pragma unroll
            for (int j = 0; j < 2; j++)
                bf[j] = *(const half8*)(BsR + (wave * 32 + j * 16 + l16) * 128 + cbB);
            #pragma unroll
            for (int i = 0; i < 4; i++) {
                acc[i][0] = __builtin_amdgcn_mfma_f32_16x16x32_f16(af[i], bf[0], acc[i][0], 0, 0, 0);
                acc[i][1] = __builtin_amdgcn_mfma_f32_16x16x32_f16(af[i], bf[1], acc[i][1], 0, 0, 0);
            }
        }
    };

    if constexpr (AF32) {
        // 4 full DMA steps (cols 0..256; all < FF=300 in-bounds)
        #pragma unroll
        for (int kk = 0; kk < 256; kk += 64) {
            glds16(ap1 + kk * 4, AsW + wave * 1024);
            glds16(ap2 + kk * 4, AsW + 8192 + wave * 1024);
            #pragma unroll
            for (int c = 0; c < 4; c++)
                glds16(bp[c] + kk * 2, BsW + (wave * 4 + c) * 1024);
            __syncthreads();
            compute();
            __syncthreads();
        }
        // tail step kk=256: B via DMA (wt zero-padded); A manual guarded staging
        #pragma unroll
        for (int c = 0; c < 4; c++)
            glds16(bp[c] + 256 * 2, BsW + (wave * 4 + c) * 1024);
        {
            int gc1 = (lane & 15) ^ (r1 & 7);
            int gc2 = (lane & 15) ^ (r2 & 7);
            float v1[4] = {0, 0, 0, 0}, v2[4] = {0, 0, 0, 0};
            #pragma unroll
            for (int j = 0; j < 4; j++) {
                int col1 = 256 + gc1 * 4 + j;
                int col2 = 256 + gc2 * 4 + j;
                if (col1 < FF) v1[j] = s1[col1];
                if (col2 < FF) v2[j] = s2[col2];
            }
            *(float4*)(AsW + r1 * 256 + (lane & 15) * 16) = make_float4(v1[0], v1[1], v1[2], v1[3]);
            *(float4*)(AsW + r2 * 256 + (lane & 15) * 16) = make_float4(v2[0], v2[1], v2[2], v2[3]);
        }
        __syncthreads();
        compute();
    } else {
        for (int kk = 0; kk < K; kk += 64) {
            glds16(ap1 + kk * 2, AsW + wave * 1024);
            #pragma unroll
            for (int c = 0; c < 4; c++)
                glds16(bp[c] + kk * 2, BsW + (wave * 4 + c) * 1024);
            __syncthreads();
            compute();
            __syncthreads();
        }
    }

    // epilogue: C/D layout col=lane&15, row=quad*4+reg (m89; dtype-independent m121)
    u16* Cw = (wave < 4) ? C1 : C2;
    const float* bw = (wave < 4) ? bias1 : bias2;
    int cb0 = (wave & 3) * 32;
    #pragma unroll
    for (int i = 0; i < 4; i++) {
        #pragma unroll
        for (int rr = 0; rr < 4; rr++) {
            int row = m0 + i * 16 + quad * 4 + rr;
            if (row < M) {
                #pragma unroll
                for (int j = 0; j < 2; j++) {
                    int col = cb0 + j * 16 + l16;
                    Cw[(size_t)row * DD + col] = f2h(acc[i][j][rr] + bw[col]);
                }
            }
        }
    }
}

// ---------------- CSR scan (two-level, add folded into consumers)
__global__ __launch_bounds__(256)
void scan_local_kernel(const int* __restrict__ counts, int* __restrict__ offsets,
                       int* __restrict__ bsum)
{
    __shared__ int lds4[4];
    int i = blockIdx.x * 256 + threadIdx.x;
    int v = (i < NN) ? counts[i] : 0;
    int total;
    int ex = block_excl_scan(v, lds4, &total);
    if (i < NN) offsets[i] = ex;
    if (threadIdx.x == 0) bsum[blockIdx.x] = total;
}

__global__ __launch_bounds__(256)
void scan_bsum_kernel(int* __restrict__ bsum)
{
    __shared__ int lds4[4];
    int t = threadIdx.x;
    int v = (t < SB) ? bsum[t] : 0;
    int total;
    int ex = block_excl_scan(v, lds4, &total);
    if (t < SB) bsum[t] = ex;
}

// ---------------- fused per-node: logits + softmax (no-shift) + aggregate + bias + act
// one wave per dst node; 4 edge-groups of 16 lanes; lane owns 8 channels (c0=(lane&15)*8)
// ALL fp16-packed math; gathers via 32-bit element offsets (saddr form, less VALU).
__global__ __launch_bounds__(256)
void node_kernel(const u32* __restrict__ dstorder, const int* __restrict__ offsets,
                 const int* __restrict__ bsum,
                 const u16* __restrict__ xl, const u16* __restrict__ xr,
                 const u16* __restrict__ erel, const float* __restrict__ att,
                 const float* __restrict__ bias,
                 u16* __restrict__ xnext, float* __restrict__ outp, int is_last)
{
    int tid  = threadIdx.x;
    int node = blockIdx.x * 4 + (tid >> 6);
    int lane = tid & 63;
    if (node >= NN) return;
    int g  = lane >> 4;          // edge slot within quad
    int gl = lane & 15;          // channel set
    int c0 = gl * 8;
    int beg = offsets[node] + bsum[node >> 8];
    int end = (node == NN - 1) ? EE : offsets[node + 1] + bsum[(node + 1) >> 8];

    // per-node constants (packed fp16)
    h2 xrh[4], atth[4];
    {
        u32x4 xrv = *(const u32x4*)(xr + ((u32)node * DD + c0));
        #pragma unroll
        for (int q = 0; q < 4; q++) xrh[q] = u2h2(xrv[q]);
        #pragma unroll
        for (int q = 0; q < 4; q++) {
            float2 av = *(const float2*)&att[c0 + q * 2];
            atth[q] = (h2){(_Float16)av.x, (_Float16)av.y};
        }
    }
    const h2 c02 = (h2){(_Float16)0.2f, (_Float16)0.2f};

    float s = 0.f;
    h2 a2[4];
    #pragma unroll
    for (int q = 0; q < 4; q++) a2[q] = (h2){(_Float16)0.f, (_Float16)0.f};

    for (int base = beg; base < end; base += 4) {
        int es = base + g;
        bool valid = es < end;
        u32 st = valid ? dstorder[es] : 0;
        // 32-bit element offsets: src*128+c0 < 6.4M, typ*128+c0 < 51200
        u32 xoff = (st & 0xffffu) * DD + (u32)c0;
        u32 eoff = (st >> 16) * DD + (u32)c0;
        u32x4 xv = *(const u32x4*)(xl + xoff);
        u32x4 ev = *(const u32x4*)(erel + eoff);
        h2 xh[4];
        float p = 0.f;
        #pragma unroll
        for (int q = 0; q < 4; q++) {
            xh[q] = u2h2(xv[q]);
            h2 m = (xh[q] + xrh[q]) + u2h2(ev[q]);   // v_pk_add_f16 x2
            m = hmax2(m, m * c02);                   // leaky: pk_mul + pk_max
            p = hdot2(m, atth[q], p);                // v_dot2_f32_f16 (fp32 acc)
        }
        // per-head logit: reduce over the 4 lanes of this head (gl span of 4)
        p += __shfl_xor(p, 1, 64);
        p += __shfl_xor(p, 2, 64);
        // softmax without max-shift: logits are O(1); clamp guards inf
        float w = valid ? __expf(fminf(p, 60.f)) : 0.f;
        s += w;
        h2 wh = (h2){(_Float16)w, (_Float16)w};
        #pragma unroll
        for (int q = 0; q < 4; q++) a2[q] += wh * xh[q];   // v_pk_fma_f16
    }

    // cross-group reduction (groups processed disjoint edges) — fp32 for safety
    float a[8];
    #pragma unroll
    for (int q = 0; q < 4; q++) { a[q*2] = (float)a2[q].x; a[q*2+1] = (float)a2[q].y; }
    #pragma unroll
    for (int j = 0; j < 8; j++) {
        a[j] += __shfl_xor(a[j], 16, 64);
        a[j] += __shfl_xor(a[j], 32, 64);
    }
    s += __shfl_xor(s, 16, 64);
    s += __shfl_xor(s, 32, 64);

    if (lane < 16) {
        float rh = 1.f / fmaxf(s, 1e-30f);
        float4 b0 = *(const float4*)&bias[c0];
        float4 b1 = *(const float4*)&bias[c0 + 4];
        float bv[8] = {b0.x, b0.y, b0.z, b0.w, b1.x, b1.y, b1.z, b1.w};
        float v[8];
        #pragma unroll
        for (int j = 0; j < 8; j++) v[j] = a[j] * rh + bv[j];
        if (is_last) {
            float4* op = (float4*)(outp + ((u32)node * DD + c0));
            op[0] = make_float4(v[0], v[1], v[2], v[3]);
            op[1] = make_float4(v[4], v[5], v[6], v[7]);
        } else {
            u16 pk[8];
            #pragma unroll
            for (int j = 0; j < 8; j++) {
                float w2 = v[j] > 0.f ? v[j] : __expf(v[j]) - 1.f;   // elu
                pk[j] = f2h(w2);
            }
            *(half8*)(xnext + ((u32)node * DD + c0)) = *(half8*)pk;
        }
    }
}

extern "C" void kernel_launch(void* const* d_in, const int* in_sizes, int n_in,
                              void* d_out, int out_size, void* d_ws, size_t ws_size,
                              hipStream_t stream)
{
    const int*   entity        = (const int*)d_in[0];
    const int*   edge_index    = (const int*)d_in[1];
    const int*   edge_type     = (const int*)d_in[2];
    const float* node_features = (const float*)d_in[3];
    const float* rel_emb       = (const float*)d_in[4];
    const float* proj_w        = (const float*)d_in[5];
    const float* proj_b        = (const float*)d_in[6];
    const float* w_l           = (const float*)d_in[7];
    const float* b_l           = (const float*)d_in[8];
    const float* w_r           = (const float*)d_in[9];
    const float* b_r           = (const float*)d_in[10];
    const float* w_e           = (const float*)d_in[11];
    const float* att           = (const float*)d_in[12];
    const float* bias          = (const float*)d_in[13];

    // workspace (~45 MB), all fp16 tensors in u16 containers:
    u16*   xb      = (u16*)d_ws;                           // NN*DD (layer-0 output / layer-1 input)
    u16*   xl      = xb + (size_t)NN * DD;                 // NN*DD
    u16*   xr      = xl + (size_t)NN * DD;                 // NN*DD
    u16*   erel    = xr + (size_t)NN * DD;                 // LL*RR*DD
    u16*   wt      = erel + (size_t)LL * RR * DD;          // WTOT: [fusedL][fusedR][wl1][wr1]
    u32*   dstorder= (u32*)(wt + WTOT);                    // EE u32 (src|type, dst-order)
    int*   counts  = (int*)(dstorder + (size_t)EE);        // NN int
    int*   rank    = counts + NN;                          // EE int (per-edge rank in dst)
    int*   offsets = rank + EE;                            // NN int (local scans)
    int*   bsum    = offsets + NN;                         // SB int
    float* fbias   = (float*)(bsum + SB);                  // 256 fp32 (folded layer-0 bias)

    // ---- prep: zero counts, then fused sections (hist captures per-edge rank)
    hipMemsetAsync(counts, 0, (size_t)NN * sizeof(int), stream);
    prep_kernel<<<PB, 256, 0, stream>>>(
        edge_index, counts, rank, proj_w, w_l, w_r, wt, rel_emb, w_e, erel,
        proj_b, b_l, b_r, fbias);

    // ---- CSR: two-level scan (scatter fused into the layer-0 GEMM launch)
    scan_local_kernel<<<SB, 256, 0, stream>>>(counts, offsets, bsum);
    scan_bsum_kernel<<<1, 256, 0, stream>>>(bsum);

    const int GB2 = (NN + 63) / 64;

    // ---- layer 0: fused {XCD-partitioned atomic-free scatter || proj-folded GEMM}
    gemm_gll_kernel<PK, true, true><<<NSC + GB2, 512, 0, stream>>>(
        node_features, entity, wt, fbias, xl,
        wt + (size_t)128 * PK, fbias + DD, xr, NN,
        edge_index, edge_type, offsets, bsum, rank, dstorder);
    node_kernel<<<(NN + 3) / 4, 256, 0, stream>>>(
        dstorder, offsets, bsum, xl, xr, erel,
        att, bias, xb, (float*)d_out, 0);

    // ---- layer 1: dual-output GEMM reads xb once
    gemm_gll_kernel<DD, false, false><<<GB2, 512, 0, stream>>>(
        xb, nullptr, wt + (size_t)2 * 128 * PK, b_l + DD, xl,
        wt + (size_t)2 * 128 * PK + 128 * 128, b_r + DD, xr, NN,
        nullptr, nullptr, nullptr, nullptr, nullptr, nullptr);
    node_kernel<<<(NN + 3) / 4, 256, 0, stream>>>(
        dstorder, offsets, bsum, xl, xr, erel + (size_t)RR * DD,
        att + DD, bias + DD, xb, (float*)d_out, 1);
}

// Round 14
// 293.584 us; speedup vs baseline: 1.0618x; 1.0618x over previous
//
#include <hip/hip_runtime.h>

#define NN 50000
#define FF 300
#define DD 128
#define HH 4
#define CC 32
#define EE 640000
#define RR 200
#define LL 2
#define SB ((NN + 255) / 256)     // scan blocks = 196
#define PK 320                    // proj K padded to multiple of 64
#define WCONV (2 * 128 * 128)     // layer-1 wl/wr transposed fp16
#define WTOT (2 * 128 * PK + WCONV)
// prep sections (chunked x4, dense per-instruction accesses)
#define HB2 (EE / 1024)           // hist blocks: 625, 4 edges/thread
#define WB2 (WCONV / 1024)        // wconv blocks: 32, 4 elems/thread
#define FB2 80                    // fold blocks: 8 k's each (4/half, shared W stream)
#define RB2 100                   // relproj blocks: 4 r's each (2/half, shared W)
#define PB (HB2 + WB2 + FB2 + 1 + RB2)   // prep grid: 838
#define NSC 157                   // scatter blocks fused into gemm0 (512 thr, 8 e/thr)

typedef unsigned short u16;
typedef unsigned int u32;
typedef unsigned long long u64;
typedef _Float16 h2   __attribute__((ext_vector_type(2)));
typedef _Float16 half8 __attribute__((ext_vector_type(8)));  // MFMA A/B frag (4 VGPRs)
typedef __attribute__((ext_vector_type(4))) float floatx4;   // MFMA accumulator
typedef u32 u32x4 __attribute__((ext_vector_type(4)));       // 16B packed-half load
typedef u32 u32x2 __attribute__((ext_vector_type(2)));

__device__ __forceinline__ u16 f2h(float f) {
    union { _Float16 h; u16 u; } v; v.h = (_Float16)f; return v.u;
}
__device__ __forceinline__ h2 u2h2(u32 p) {
    union { u32 u; h2 h; } v; v.u = p; return v.h;
}
__device__ __forceinline__ h2 hmax2(h2 a, h2 b) {
#if __has_builtin(__builtin_elementwise_max)
    return __builtin_elementwise_max(a, b);
#else
    h2 r; r.x = a.x > b.x ? a.x : b.x; r.y = a.y > b.y ? a.y : b.y; return r;
#endif
}
__device__ __forceinline__ float hdot2(h2 a, h2 b, float c) {
#if __has_builtin(__builtin_amdgcn_fdot2)
    return __builtin_amdgcn_fdot2(a, b, c, false);
#else
    return c + (float)a.x * (float)b.x + (float)a.y * (float)b.y;
#endif
}
// async global->LDS DMA, 16 B per lane; dest = lds_base + lane*16 (wave-uniform base)
__device__ __forceinline__ void glds16(const void* g, void* l) {
    using gp = const unsigned int __attribute__((address_space(1)))*;
    using lp = unsigned int __attribute__((address_space(3)))*;
    __builtin_amdgcn_global_load_lds((gp)(u64)g, (lp)(u64)l, 16, 0, 0);
}

// block-wide (256 threads) scan: returns exclusive prefix of v; *total = block sum
__device__ __forceinline__ int block_excl_scan(int v, int* lds4, int* total) {
    int lane = threadIdx.x & 63, wid = threadIdx.x >> 6;
    int x = v;
    #pragma unroll
    for (int off = 1; off < 64; off <<= 1) {
        int y = __shfl_up(x, off, 64);
        if (lane >= off) x += y;
    }
    if (lane == 63) lds4[wid] = x;
    __syncthreads();
    int add = 0;
    #pragma unroll
    for (int w = 0; w < 4; w++) add += (w < wid) ? lds4[w] : 0;
    *total = lds4[0] + lds4[1] + lds4[2] + lds4[3];
    return x + add - v;
}

// ---------------- fused prep:
// hist+rank | layer1 wconv | layer0 fold (8k/blk, shared W) | biasfold | relproj
// hist KEEPS the atomic return value: rank[e] = edge's arrival index within its
// dst -> the later scatter needs NO atomic at all (pos = offsets+bsum+rank).
__global__ __launch_bounds__(256)
void prep_kernel(const int* __restrict__ ei, int* __restrict__ counts,
                 int* __restrict__ rank,
                 const float* __restrict__ proj_w, const float* __restrict__ w_l,
                 const float* __restrict__ w_r, u16* __restrict__ wt,
                 const float* __restrict__ rel_emb, const float* __restrict__ w_e,
                 u16* __restrict__ erel, const float* __restrict__ proj_b,
                 const float* __restrict__ b_l, const float* __restrict__ b_r,
                 float* __restrict__ fbias)
{
    __shared__ float sm[8 * DD];   // 4 KB scratch, aliased per section
    int b = blockIdx.x, tid = threadIdx.x;
    if (b < HB2) {
        // degree histogram + per-edge rank capture: 4 edges/thread
        #pragma unroll
        for (int j = 0; j < 4; j++) {
            int e = b * 1024 + j * 256 + tid;            // < EE exactly
            int r = atomicAdd(&counts[ei[EE + e]], 1);
            rank[e] = r;                                 // coalesced 4B store
        }
    } else if (b < HB2 + WB2) {
        // layer-1 weights: fp32 [k][n] -> fp16 wt[n][k], segs [wl1][wr1]; 4/thread
        #pragma unroll
        for (int j = 0; j < 4; j++) {
            int i = (b - HB2) * 1024 + j * 256 + tid;    // < 32768 exactly
            int seg = i >> 14;                           // 0 = wl1, 1 = wr1
            int r = i & 16383;
            int n = r >> 7, k = r & 127;
            const float* src = (seg == 0 ? w_l : w_r) + (size_t)DD * DD;  // layer 1
            wt[2 * 128 * PK + i] = f2h(src[(size_t)k * DD + n]);
        }
    } else if (b < HB2 + WB2 + FB2) {
        // fused layer-0 weights: F[k][n] = sum_j Wp[k][j]*W{l,r}0[j][n]
        // block: one lr, 8 k's (half handles 4, sharing one W-column stream)
        int bb = b - HB2 - WB2;
        int lr = bb / 40, kg = bb % 40;
        int half = tid >> 7, d = tid & 127;
        int k0 = kg * 8 + half * 4;
        float* rv = sm + half * 4 * DD;
        #pragma unroll
        for (int kk = 0; kk < 4; kk++)
            rv[kk * DD + d] = (k0 + kk < FF) ? proj_w[(size_t)(k0 + kk) * DD + d] : 0.f;
        __syncthreads();
        const float* W = lr ? w_r : w_l;                 // layer 0
        float acc[4] = {0.f, 0.f, 0.f, 0.f};
        #pragma unroll 8
        for (int j = 0; j < DD; j++) {
            float wv = W[(size_t)j * DD + d];
            #pragma unroll
            for (int kk = 0; kk < 4; kk++) acc[kk] += rv[kk * DD + j] * wv;
        }
        u16 o[4];
        #pragma unroll
        for (int kk = 0; kk < 4; kk++) o[kk] = f2h(acc[kk]);
        *(u32x2*)(wt + (size_t)lr * 128 * PK + (size_t)d * PK + k0) = *(u32x2*)o;
    } else if (b == HB2 + WB2 + FB2) {
        // fused layer-0 bias: fb = b_{l,r}0 + proj_b @ W{l,r}0  (fp32)
        int half = tid >> 7, d = tid & 127;
        if (tid < DD) sm[tid] = proj_b[tid];
        __syncthreads();
        const float* W = half ? w_r : w_l;
        float acc = half ? b_r[d] : b_l[d];
        #pragma unroll 8
        for (int j = 0; j < DD; j++) acc += sm[j] * W[(size_t)j * DD + d];
        fbias[half * DD + d] = acc;
    } else {
        // erel[(l*RR+r)][d] = rel_emb[r,:] @ w_e[l][:,d]
        // block: one l, 4 r's (half handles 2, sharing W stream)
        int bb = b - (HB2 + WB2 + FB2 + 1);
        int l = bb / 50, rg = bb % 50;
        int half = tid >> 7, d = tid & 127;
        int r0 = rg * 4 + half * 2;
        float* rv = sm + half * 2 * DD;
        #pragma unroll
        for (int rr = 0; rr < 2; rr++)
            rv[rr * DD + d] = rel_emb[(size_t)(r0 + rr) * DD + d];
        __syncthreads();
        const float* W = w_e + (size_t)l * DD * DD;
        float acc[2] = {0.f, 0.f};
        #pragma unroll 8
        for (int j = 0; j < DD; j++) {
            float wv = W[(size_t)j * DD + d];
            #pragma unroll
            for (int rr = 0; rr < 2; rr++) acc[rr] += rv[rr * DD + j] * wv;
        }
        #pragma unroll
        for (int rr = 0; rr < 2; rr++)
            erel[(size_t)(l * RR + r0 + rr) * DD + d] = f2h(acc[rr]);
    }
}

// ---------------- dual-output MFMA GEMM, global_load_lds staging, 64x256 tile,
// 8 waves (wave owns 32 cols; waves 0-3 -> C1, 4-7 -> C2), BK=64, 2 barriers/step.
// AF32=false: A fp16 [M][K] direct (xb), 1 A-DMA/thread/step, 8KB A-LDS.
// AF32=true : A fp32 gathered from nf via rowidx (convert folded into fragment
//   load, RTE-identical to a pre-converted table). Tail cols 256..319 guarded.
// FUSE: blocks [0,NSC) run the round-11 ATOMIC-FREE scatter (rank precomputed in
//   prep's hist): single pass, 8 edges/thread, 1 fire-and-forget 4B write/edge.
//   (Round-13's XCD-partitioned variant cut WRITE 49->32MB but inflated FETCH
//   38->72MB -> net regression; reverted.)
template<int K, bool AF32, bool FUSE>
__global__ __launch_bounds__(512)
void gemm_gll_kernel(const void* __restrict__ A_, const int* __restrict__ rowidx,
                     const u16* __restrict__ BT1, const float* __restrict__ bias1,
                     u16* __restrict__ C1,
                     const u16* __restrict__ BT2, const float* __restrict__ bias2,
                     u16* __restrict__ C2, int M,
                     const int* __restrict__ ei, const int* __restrict__ et,
                     const int* __restrict__ offsets, const int* __restrict__ bsum,
                     const int* __restrict__ rank, u32* __restrict__ dstorder)
{
    __shared__ float AsF[AF32 ? 4096 : 2048];   // 16 KB fp32 | 8 KB fp16
    __shared__ u16 Bs[256 * 64];                // 32 KB
    int tid  = threadIdx.x;
    if constexpr (FUSE) {
        if (blockIdx.x < NSC) {
            // CSR scatter: 8 edges/thread, no atomics, independent iterations
            #pragma unroll
            for (int j = 0; j < 8; j++) {
                int e = blockIdx.x * 4096 + j * 512 + tid;
                if (e < EE) {
                    int d = ei[EE + e];
                    int pos = offsets[d] + bsum[d >> 8] + rank[e];
                    dstorder[pos] = (u32)ei[e] | ((u32)et[e] << 16);
                }
            }
            return;
        }
    }
    int bid  = FUSE ? ((int)blockIdx.x - NSC) : (int)blockIdx.x;
    int m0   = bid * 64;
    int wave = tid >> 6, lane = tid & 63;
    int quad = lane >> 4, l16 = lane & 15;

    floatx4 acc[4][2];
    #pragma unroll
    for (int i = 0; i < 4; i++)
        #pragma unroll
        for (int j = 0; j < 2; j++) acc[i][j] = (floatx4){0.f, 0.f, 0.f, 0.f};

    // ---- B staging source pointers (per lane, swizzled); ldb == K
    const char* bp[4];
    #pragma unroll
    for (int c = 0; c < 4; c++) {
        int rowB = wave * 32 + c * 8 + (lane >> 3);   // 0..255
        const u16* base = (rowB < 128) ? BT1 : BT2;
        int br = rowB & 127;
        bp[c] = (const char*)(base + (size_t)br * K)
              + (((lane & 7) << 4) ^ ((br & 7) << 4));
    }
    char* AsW = (char*)AsF;
    char* BsW = (char*)Bs;
    const char* AsR = (const char*)AsF;
    const char* BsR = (const char*)Bs;

    // ---- A staging source pointers
    const char* ap1; const char* ap2; const float* s1; const float* s2;
    int r1, r2;
    if constexpr (AF32) {
        r1 = wave * 4 + (lane >> 4);                 // rows 0..31
        r2 = r1 + 32;                                // rows 32..63
        int g1 = m0 + r1; if (g1 >= M) g1 = M - 1;
        int g2 = m0 + r2; if (g2 >= M) g2 = M - 1;
        s1 = (const float*)A_ + (size_t)rowidx[g1] * FF;
        s2 = (const float*)A_ + (size_t)rowidx[g2] * FF;
        ap1 = (const char*)s1 + (((lane & 15) ^ (r1 & 7)) * 16);
        ap2 = (const char*)s2 + (((lane & 15) ^ (r2 & 7)) * 16);
    } else {
        int arl = wave * 8 + (lane >> 3);
        int arg = m0 + arl; if (arg >= M) arg = M - 1;
        ap1 = (const char*)((const u16*)A_ + (size_t)arg * K)
            + (((lane & 7) << 4) ^ ((arl & 7) << 4));
        ap2 = nullptr; s1 = s2 = nullptr; r1 = r2 = 0;
    }
    int axor16 = (l16 & 7) << 4;

    // compute phase for one 64-col LDS tile (cols kk..kk+64 resident)
    auto compute = [&]() {
        #pragma unroll
        for (int s2i = 0; s2i < 2; s2i++) {
            half8 af[4], bf[2];
            if constexpr (AF32) {
                int c0 = s2i * 8 + quad * 2;           // 16B chunk idx (4 floats)
                #pragma unroll
                for (int i = 0; i < 4; i++) {
                    int row = i * 16 + l16;
                    const char* rb = AsR + row * 256;
                    float4 lo = *(const float4*)(rb + ((c0 ^ (row & 7)) * 16));
                    float4 hi = *(const float4*)(rb + (((c0 + 1) ^ (row & 7)) * 16));
                    u16 o[8];
                    o[0] = f2h(lo.x); o[1] = f2h(lo.y); o[2] = f2h(lo.z); o[3] = f2h(lo.w);
                    o[4] = f2h(hi.x); o[5] = f2h(hi.y); o[6] = f2h(hi.z); o[7] = f2h(hi.w);
                    af[i] = *(half8*)o;
                }
            } else {
                int cb = (s2i * 64 + quad * 16) ^ axor16;
                #pragma unroll
                for (int i = 0; i < 4; i++)
                    af[i] = *(const half8*)(AsR + (i * 16 + l16) * 128 + cb);
            }
            int cbB = (s2i * 64 + quad * 16) ^ axor16;
            #pragma unroll
            for (int j = 0; j < 2; j++)
                bf[j] = *(const half8*)(BsR + (wave * 32 + j * 16 + l16) * 128 + cbB);
            #pragma unroll
            for (int i = 0; i < 4; i++) {
                acc[i][0] = __builtin_amdgcn_mfma_f32_16x16x32_f16(af[i], bf[0], acc[i][0], 0, 0, 0);
                acc[i][1] = __builtin_amdgcn_mfma_f32_16x16x32_f16(af[i], bf[1], acc[i][1], 0, 0, 0);
            }
        }
    };

    if constexpr (AF32) {
        // 4 full DMA steps (cols 0..256; all < FF=300 in-bounds)
        #pragma unroll
        for (int kk = 0; kk < 256; kk += 64) {
            glds16(ap1 + kk * 4, AsW + wave * 1024);
            glds16(ap2 + kk * 4, AsW + 8192 + wave * 1024);
            #pragma unroll
            for (int c = 0; c < 4; c++)
                glds16(bp[c] + kk * 2, BsW + (wave * 4 + c) * 1024);
            __syncthreads();
            compute();
            __syncthreads();
        }
        // tail step kk=256: B via DMA (wt zero-padded); A manual guarded staging
        #pragma unroll
        for (int c = 0; c < 4; c++)
            glds16(bp[c] + 256 * 2, BsW + (wave * 4 + c) * 1024);
        {
            int gc1 = (lane & 15) ^ (r1 & 7);
            int gc2 = (lane & 15) ^ (r2 & 7);
            float v1[4] = {0, 0, 0, 0}, v2[4] = {0, 0, 0, 0};
            #pragma unroll
            for (int j = 0; j < 4; j++) {
                int col1 = 256 + gc1 * 4 + j;
                int col2 = 256 + gc2 * 4 + j;
                if (col1 < FF) v1[j] = s1[col1];
                if (col2 < FF) v2[j] = s2[col2];
            }
            *(float4*)(AsW + r1 * 256 + (lane & 15) * 16) = make_float4(v1[0], v1[1], v1[2], v1[3]);
            *(float4*)(AsW + r2 * 256 + (lane & 15) * 16) = make_float4(v2[0], v2[1], v2[2], v2[3]);
        }
        __syncthreads();
        compute();
    } else {
        for (int kk = 0; kk < K; kk += 64) {
            glds16(ap1 + kk * 2, AsW + wave * 1024);
            #pragma unroll
            for (int c = 0; c < 4; c++)
                glds16(bp[c] + kk * 2, BsW + (wave * 4 + c) * 1024);
            __syncthreads();
            compute();
            __syncthreads();
        }
    }

    // epilogue: C/D layout col=lane&15, row=quad*4+reg (m89; dtype-independent m121)
    u16* Cw = (wave < 4) ? C1 : C2;
    const float* bw = (wave < 4) ? bias1 : bias2;
    int cb0 = (wave & 3) * 32;
    #pragma unroll
    for (int i = 0; i < 4; i++) {
        #pragma unroll
        for (int rr = 0; rr < 4; rr++) {
            int row = m0 + i * 16 + quad * 4 + rr;
            if (row < M) {
                #pragma unroll
                for (int j = 0; j < 2; j++) {
                    int col = cb0 + j * 16 + l16;
                    Cw[(size_t)row * DD + col] = f2h(acc[i][j][rr] + bw[col]);
                }
            }
        }
    }
}

// ---------------- CSR scan (two-level, add folded into consumers)
__global__ __launch_bounds__(256)
void scan_local_kernel(const int* __restrict__ counts, int* __restrict__ offsets,
                       int* __restrict__ bsum)
{
    __shared__ int lds4[4];
    int i = blockIdx.x * 256 + threadIdx.x;
    int v = (i < NN) ? counts[i] : 0;
    int total;
    int ex = block_excl_scan(v, lds4, &total);
    if (i < NN) offsets[i] = ex;
    if (threadIdx.x == 0) bsum[blockIdx.x] = total;
}

__global__ __launch_bounds__(256)
void scan_bsum_kernel(int* __restrict__ bsum)
{
    __shared__ int lds4[4];
    int t = threadIdx.x;
    int v = (t < SB) ? bsum[t] : 0;
    int total;
    int ex = block_excl_scan(v, lds4, &total);
    if (t < SB) bsum[t] = ex;
}

// ---------------- fused per-node: logits + softmax (no-shift) + aggregate + bias + act
// one wave per dst node; 4 edge-groups of 16 lanes; lane owns 8 channels (c0=(lane&15)*8)
// ALL fp16-packed math; 32-bit gather offsets; dstorder INDEX PREFETCHED one
// iteration ahead (1 VGPR) so the index->gather dependent chain overlaps the
// previous iteration's math instead of serializing with it.
__global__ __launch_bounds__(256)
void node_kernel(const u32* __restrict__ dstorder, const int* __restrict__ offsets,
                 const int* __restrict__ bsum,
                 const u16* __restrict__ xl, const u16* __restrict__ xr,
                 const u16* __restrict__ erel, const float* __restrict__ att,
                 const float* __restrict__ bias,
                 u16* __restrict__ xnext, float* __restrict__ outp, int is_last)
{
    int tid  = threadIdx.x;
    int node = blockIdx.x * 4 + (tid >> 6);
    int lane = tid & 63;
    if (node >= NN) return;
    int g  = lane >> 4;          // edge slot within quad
    int gl = lane & 15;          // channel set
    int c0 = gl * 8;
    int beg = offsets[node] + bsum[node >> 8];
    int end = (node == NN - 1) ? EE : offsets[node + 1] + bsum[(node + 1) >> 8];

    // per-node constants (packed fp16)
    h2 xrh[4], atth[4];
    {
        u32x4 xrv = *(const u32x4*)(xr + ((u32)node * DD + c0));
        #pragma unroll
        for (int q = 0; q < 4; q++) xrh[q] = u2h2(xrv[q]);
        #pragma unroll
        for (int q = 0; q < 4; q++) {
            float2 av = *(const float2*)&att[c0 + q * 2];
            atth[q] = (h2){(_Float16)av.x, (_Float16)av.y};
        }
    }
    const h2 c02 = (h2){(_Float16)0.2f, (_Float16)0.2f};

    float s = 0.f;
    h2 a2[4];
    #pragma unroll
    for (int q = 0; q < 4; q++) a2[q] = (h2){(_Float16)0.f, (_Float16)0.f};

    // prefetch the first dstorder word
    u32 stN = (beg + g < end) ? dstorder[beg + g] : 0;

    for (int base = beg; base < end; base += 4) {
        u32 st = stN;
        bool valid = (base + g) < end;
        // issue next iteration's index load BEFORE this iteration's gather chain
        int esn = base + 4 + g;
        stN = (esn < end) ? dstorder[esn] : 0;
        // 32-bit element offsets: src*128+c0 < 6.4M, typ*128+c0 < 51200
        u32 xoff = (st & 0xffffu) * DD + (u32)c0;
        u32 eoff = (st >> 16) * DD + (u32)c0;
        u32x4 xv = *(const u32x4*)(xl + xoff);
        u32x4 ev = *(const u32x4*)(erel + eoff);
        h2 xh[4];
        float p = 0.f;
        #pragma unroll
        for (int q = 0; q < 4; q++) {
            xh[q] = u2h2(xv[q]);
            h2 m = (xh[q] + xrh[q]) + u2h2(ev[q]);   // v_pk_add_f16 x2
            m = hmax2(m, m * c02);                   // leaky: pk_mul + pk_max
            p = hdot2(m, atth[q], p);                // v_dot2_f32_f16 (fp32 acc)
        }
        // per-head logit: reduce over the 4 lanes of this head (gl span of 4)
        p += __shfl_xor(p, 1, 64);
        p += __shfl_xor(p, 2, 64);
        // softmax without max-shift: logits are O(1); clamp guards inf
        float w = valid ? __expf(fminf(p, 60.f)) : 0.f;
        s += w;
        h2 wh = (h2){(_Float16)w, (_Float16)w};
        #pragma unroll
        for (int q = 0; q < 4; q++) a2[q] += wh * xh[q];   // v_pk_fma_f16
    }

    // cross-group reduction (groups processed disjoint edges) — fp32 for safety
    float a[8];
    #pragma unroll
    for (int q = 0; q < 4; q++) { a[q*2] = (float)a2[q].x; a[q*2+1] = (float)a2[q].y; }
    #pragma unroll
    for (int j = 0; j < 8; j++) {
        a[j] += __shfl_xor(a[j], 16, 64);
        a[j] += __shfl_xor(a[j], 32, 64);
    }
    s += __shfl_xor(s, 16, 64);
    s += __shfl_xor(s, 32, 64);

    if (lane < 16) {
        float rh = 1.f / fmaxf(s, 1e-30f);
        float4 b0 = *(const float4*)&bias[c0];
        float4 b1 = *(const float4*)&bias[c0 + 4];
        float bv[8] = {b0.x, b0.y, b0.z, b0.w, b1.x, b1.y, b1.z, b1.w};
        float v[8];
        #pragma unroll
        for (int j = 0; j < 8; j++) v[j] = a[j] * rh + bv[j];
        if (is_last) {
            float4* op = (float4*)(outp + ((u32)node * DD + c0));
            op[0] = make_float4(v[0], v[1], v[2], v[3]);
            op[1] = make_float4(v[4], v[5], v[6], v[7]);
        } else {
            u16 pk[8];
            #pragma unroll
            for (int j = 0; j < 8; j++) {
                float w2 = v[j] > 0.f ? v[j] : __expf(v[j]) - 1.f;   // elu
                pk[j] = f2h(w2);
            }
            *(half8*)(xnext + ((u32)node * DD + c0)) = *(half8*)pk;
        }
    }
}

extern "C" void kernel_launch(void* const* d_in, const int* in_sizes, int n_in,
                              void* d_out, int out_size, void* d_ws, size_t ws_size,
                              hipStream_t stream)
{
    const int*   entity        = (const int*)d_in[0];
    const int*   edge_index    = (const int*)d_in[1];
    const int*   edge_type     = (const int*)d_in[2];
    const float* node_features = (const float*)d_in[3];
    const float* rel_emb       = (const float*)d_in[4];
    const float* proj_w        = (const float*)d_in[5];
    const float* proj_b        = (const float*)d_in[6];
    const float* w_l           = (const float*)d_in[7];
    const float* b_l           = (const float*)d_in[8];
    const float* w_r           = (const float*)d_in[9];
    const float* b_r           = (const float*)d_in[10];
    const float* w_e           = (const float*)d_in[11];
    const float* att           = (const float*)d_in[12];
    const float* bias          = (const float*)d_in[13];

    // workspace (~45 MB), all fp16 tensors in u16 containers:
    u16*   xb      = (u16*)d_ws;                           // NN*DD (layer-0 output / layer-1 input)
    u16*   xl      = xb + (size_t)NN * DD;                 // NN*DD
    u16*   xr      = xl + (size_t)NN * DD;                 // NN*DD
    u16*   erel    = xr + (size_t)NN * DD;                 // LL*RR*DD
    u16*   wt      = erel + (size_t)LL * RR * DD;          // WTOT: [fusedL][fusedR][wl1][wr1]
    u32*   dstorder= (u32*)(wt + WTOT);                    // EE u32 (src|type, dst-order)
    int*   counts  = (int*)(dstorder + (size_t)EE);        // NN int
    int*   rank    = counts + NN;                          // EE int (per-edge rank in dst)
    int*   offsets = rank + EE;                            // NN int (local scans)
    int*   bsum    = offsets + NN;                         // SB int
    float* fbias   = (float*)(bsum + SB);                  // 256 fp32 (folded layer-0 bias)

    // ---- prep: zero counts, then fused sections (hist captures per-edge rank)
    hipMemsetAsync(counts, 0, (size_t)NN * sizeof(int), stream);
    prep_kernel<<<PB, 256, 0, stream>>>(
        edge_index, counts, rank, proj_w, w_l, w_r, wt, rel_emb, w_e, erel,
        proj_b, b_l, b_r, fbias);

    // ---- CSR: two-level scan (scatter fused into the layer-0 GEMM launch)
    scan_local_kernel<<<SB, 256, 0, stream>>>(counts, offsets, bsum);
    scan_bsum_kernel<<<1, 256, 0, stream>>>(bsum);

    const int GB2 = (NN + 63) / 64;

    // ---- layer 0: fused {atomic-free CSR scatter || proj-folded GEMM}
    gemm_gll_kernel<PK, true, true><<<NSC + GB2, 512, 0, stream>>>(
        node_features, entity, wt, fbias, xl,
        wt + (size_t)128 * PK, fbias + DD, xr, NN,
        edge_index, edge_type, offsets, bsum, rank, dstorder);
    node_kernel<<<(NN + 3) / 4, 256, 0, stream>>>(
        dstorder, offsets, bsum, xl, xr, erel,
        att, bias, xb, (float*)d_out, 0);

    // ---- layer 1: dual-output GEMM reads xb once
    gemm_gll_kernel<DD, false, false><<<GB2, 512, 0, stream>>>(
        xb, nullptr, wt + (size_t)2 * 128 * PK, b_l + DD, xl,
        wt + (size_t)2 * 128 * PK + 128 * 128, b_r + DD, xr, NN,
        nullptr, nullptr, nullptr, nullptr, nullptr, nullptr);
    node_kernel<<<(NN + 3) / 4, 256, 0, stream>>>(
        dstorder, offsets, bsum, xl, xr, erel + (size_t)RR * DD,
        att + DD, bias + DD, xb, (float*)d_out, 1);
}